// Round 4
// baseline (239.561 us; speedup 1.0000x reference)
//
#include <hip/hip_runtime.h>
#include <hip/hip_bf16.h>
#include <stdint.h>

// PixproLoss: out = -(sum_masked cos_sim / count_mask), B=2048, C=256, P=49.
// m2[c,p] = sum_q (mask[p,q]*inv_nm[q]) * m[c,q]  (MFMA, contraction over q)
// num_b   = sum_p inv_nb[p] * sum_c b[c,p]*m2[c,p]
// R4: ALL global loads (m, A, b) hoisted to block head; b-norms computed in head;
// inv_nm/inv_nb finalized on parallel waves; per-wave partials -> ws (no reduce tail).

typedef __attribute__((ext_vector_type(8))) short short8;
typedef __attribute__((ext_vector_type(4))) float floatx4;

#define P 49
#define CP 12544           // C*P
#define NMASK 2401         // P*P
#define MS_STRIDE 72       // maskS LDS row stride (bf16)

__device__ __forceinline__ short8 cvt8(float4 a, float4 b) {
  union { __hip_bfloat162 h2; short s2[2]; } t;
  short8 r;
  t.h2 = __float22bfloat162_rn(make_float2(a.x, a.y)); r[0] = t.s2[0]; r[1] = t.s2[1];
  t.h2 = __float22bfloat162_rn(make_float2(a.z, a.w)); r[2] = t.s2[0]; r[3] = t.s2[1];
  t.h2 = __float22bfloat162_rn(make_float2(b.x, b.y)); r[4] = t.s2[0]; r[5] = t.s2[1];
  t.h2 = __float22bfloat162_rn(make_float2(b.z, b.w)); r[6] = t.s2[0]; r[7] = t.s2[1];
  return r;
}

__global__ __launch_bounds__(512, 4) void pixpro_main(
    const float* __restrict__ base, const float* __restrict__ moment,
    const int* __restrict__ A, float* __restrict__ ws_num, float* __restrict__ ws_cnt)
{
  __shared__ __align__(16) uint16_t maskS[P * MS_STRIDE];   // 7.1 KB
  __shared__ __align__(16) float normred[32 * 64];          // m-norm partials: 8 KB
  __shared__ __align__(16) float nbred[32 * 16];            // b-norm partials: 2 KB
  __shared__ __align__(16) float inv_nm_s[64];
  __shared__ __align__(16) float inv_nb_s[64];              // 49 used

  const int b    = blockIdx.x;
  const int tid  = threadIdx.x;
  const int lane = tid & 63;
  const int wv   = tid >> 6;          // 0..7
  const int mrow = lane & 15;
  const int kgrp = (lane >> 4) & 3;

  const float* gb = base   + (size_t)b * CP;
  const float* gm = moment + (size_t)b * CP;
  const int*   gA = A      + (size_t)b * NMASK;

  const int pbase[4] = {0, 16, 32, 33};

  // ======== PHASE 1: hoist ALL global loads ========

  // -- m fragments (A-operand) + per-q nm^2 partials (verified R3 code) --
  short8 afrag[2][2];
  float s0[8], s1[8];
  #pragma unroll
  for (int j = 0; j < 8; ++j) { s0[j] = 0.f; s1[j] = 0.f; }
  #pragma unroll
  for (int cti = 0; cti < 2; ++cti) {
    const int c = (2 * wv + cti) * 16 + mrow;
    const float* row = gm + c * P;
    float4 a0 = *(const float4*)(row + kgrp * 8);
    float4 a1 = *(const float4*)(row + kgrp * 8 + 4);
    float4 b0, b1;
    if (kgrp < 2) {
      b0 = *(const float4*)(row + 32 + kgrp * 8);
      b1 = *(const float4*)(row + 32 + kgrp * 8 + 4);
    } else if (kgrp == 2) {
      b0 = make_float4(row[48], 0.f, 0.f, 0.f);
      b1 = make_float4(0.f, 0.f, 0.f, 0.f);
    } else {
      b0 = make_float4(0.f, 0.f, 0.f, 0.f);
      b1 = make_float4(0.f, 0.f, 0.f, 0.f);
    }
    s0[0] = fmaf(a0.x, a0.x, s0[0]); s0[1] = fmaf(a0.y, a0.y, s0[1]);
    s0[2] = fmaf(a0.z, a0.z, s0[2]); s0[3] = fmaf(a0.w, a0.w, s0[3]);
    s0[4] = fmaf(a1.x, a1.x, s0[4]); s0[5] = fmaf(a1.y, a1.y, s0[5]);
    s0[6] = fmaf(a1.z, a1.z, s0[6]); s0[7] = fmaf(a1.w, a1.w, s0[7]);
    s1[0] = fmaf(b0.x, b0.x, s1[0]); s1[1] = fmaf(b0.y, b0.y, s1[1]);
    s1[2] = fmaf(b0.z, b0.z, s1[2]); s1[3] = fmaf(b0.w, b0.w, s1[3]);
    s1[4] = fmaf(b1.x, b1.x, s1[4]); s1[5] = fmaf(b1.y, b1.y, s1[5]);
    s1[6] = fmaf(b1.z, b1.z, s1[6]); s1[7] = fmaf(b1.w, b1.w, s1[7]);
    afrag[cti][0] = cvt8(a0, a1);
    afrag[cti][1] = cvt8(b0, b1);
  }

  // -- mask loads (verified R3 code) --
  const bool btask = tid < P * 8;
  const int  bp    = tid >> 3;
  const int  bqg   = tid & 7;
  const int  bq0   = bqg * 8;
  int bmask[8];
  #pragma unroll
  for (int j = 0; j < 8; ++j) bmask[j] = 0;
  if (btask) {
    const int* Ar = gA + bp * P + bq0;
    if (bqg <= 5) {
      int4 u0 = *(const int4*)(Ar);
      int4 u1 = *(const int4*)(Ar + 4);
      bmask[0] = u0.x; bmask[1] = u0.y; bmask[2] = u0.z; bmask[3] = u0.w;
      bmask[4] = u1.x; bmask[5] = u1.y; bmask[6] = u1.z; bmask[7] = u1.w;
    } else if (bqg == 6) {
      bmask[0] = Ar[0];
    }
  }

  // -- b loads (HOISTED; were post-MFMA in R3): b[c][pd], 32 scalars, coalesced across mrow --
  float bv[2][4][4];
  #pragma unroll
  for (int cti = 0; cti < 2; ++cti)
    #pragma unroll
    for (int pt = 0; pt < 4; ++pt) {
      const int pd = pbase[pt] + mrow;                // <= 48; index always in-bounds
      #pragma unroll
      for (int r = 0; r < 4; ++r) {
        const int c = (2 * wv + cti) * 16 + kgrp * 4 + r;
        bv[cti][pt][r] = gb[c * P + pd];
      }
    }
  // dedup tile 3 (rows 33..47 duplicate tile 2): keep only pd==48 (mrow==15)
  if (mrow != 15) {
    #pragma unroll
    for (int cti = 0; cti < 2; ++cti)
      #pragma unroll
      for (int r = 0; r < 4; ++r) bv[cti][3][r] = 0.f;
  }

  // ======== norm partials -> LDS ========

  // m-norms (verified R3 code)
  #pragma unroll
  for (int j = 0; j < 8; ++j) {
    s0[j] += __shfl_xor(s0[j], 1); s0[j] += __shfl_xor(s0[j], 2);
    s1[j] += __shfl_xor(s1[j], 1); s1[j] += __shfl_xor(s1[j], 2);
  }
  if ((lane & 3) == 0) {
    const int h = mrow >> 2;
    float* nb_ = &normred[(wv * 4 + h) * 64 + kgrp * 8];
    *(float4*)(nb_ + 0)  = make_float4(s0[0], s0[1], s0[2], s0[3]);
    *(float4*)(nb_ + 4)  = make_float4(s0[4], s0[5], s0[6], s0[7]);
    *(float4*)(nb_ + 32) = make_float4(s1[0], s1[1], s1[2], s1[3]);
    *(float4*)(nb_ + 36) = make_float4(s1[4], s1[5], s1[6], s1[7]);
  }

  // b-norms: sq[pt] = sum over this lane's 8 c's; reduce kgrp by shfl; bins [wv*4+pt][mrow]
  float sq[4];
  #pragma unroll
  for (int pt = 0; pt < 4; ++pt) {
    float s = 0.f;
    #pragma unroll
    for (int cti = 0; cti < 2; ++cti)
      #pragma unroll
      for (int r = 0; r < 4; ++r) { float f = bv[cti][pt][r]; s = fmaf(f, f, s); }
    s += __shfl_xor(s, 16); s += __shfl_xor(s, 32);
    sq[pt] = s;
  }
  if (lane < 16) {
    #pragma unroll
    for (int pt = 0; pt < 4; ++pt) nbred[(wv * 4 + pt) * 16 + mrow] = sq[pt];
  }
  __syncthreads();   // barrier 1

  // ======== finalize norms: wave0 -> inv_nm, wave1 -> inv_nb (parallel) ========
  if (tid < 64) {
    float s = 0.f;
    #pragma unroll
    for (int wh = 0; wh < 32; ++wh) s += normred[wh * 64 + tid];
    inv_nm_s[tid] = 1.0f / fmaxf(sqrtf(s), 1e-6f);
  } else if (tid < 128) {
    const int p = tid - 64;
    if (p < P) {
      const int pt = (p == 48) ? 3 : (p >> 4);
      const int mr = (p == 48) ? 15 : (p & 15);
      float s = 0.f;
      #pragma unroll
      for (int w = 0; w < 8; ++w) s += nbred[(w * 4 + pt) * 16 + mr];
      inv_nb_s[p] = 1.0f / fmaxf(sqrtf(s), 1e-6f);
    }
  }
  __syncthreads();   // barrier 2

  // ======== maskS build (verified R3 code) + everyone grabs inv_nb ========
  int cntpart = 0;
  if (btask) {
    float4 i0 = *(const float4*)&inv_nm_s[bq0];
    float4 i1 = *(const float4*)&inv_nm_s[bq0 + 4];
    float4 f0, f1;
    f0.x = bmask[0] ? i0.x : 0.f; f0.y = bmask[1] ? i0.y : 0.f;
    f0.z = bmask[2] ? i0.z : 0.f; f0.w = bmask[3] ? i0.w : 0.f;
    f1.x = bmask[4] ? i1.x : 0.f; f1.y = bmask[5] ? i1.y : 0.f;
    f1.z = bmask[6] ? i1.z : 0.f; f1.w = bmask[7] ? i1.w : 0.f;
    #pragma unroll
    for (int j = 0; j < 8; ++j) cntpart += bmask[j];
    *(short8*)&maskS[bp * MS_STRIDE + bq0] = cvt8(f0, f1);
  }
  float inb[4];
  #pragma unroll
  for (int pt = 0; pt < 4; ++pt) inb[pt] = inv_nb_s[pbase[pt] + mrow];
  __syncthreads();   // barrier 3

  // ======== MFMA (verified R3 code) ========
  floatx4 acc[2][4];
  #pragma unroll
  for (int i = 0; i < 2; ++i)
    #pragma unroll
    for (int j = 0; j < 4; ++j) acc[i][j] = (floatx4){0.f, 0.f, 0.f, 0.f};
  #pragma unroll
  for (int kt = 0; kt < 2; ++kt) {
    short8 bfr[4];
    #pragma unroll
    for (int pt = 0; pt < 4; ++pt)
      bfr[pt] = *(const short8*)&maskS[(pbase[pt] + mrow) * MS_STRIDE + kt * 32 + kgrp * 8];
    #pragma unroll
    for (int cti = 0; cti < 2; ++cti)
      #pragma unroll
      for (int pt = 0; pt < 4; ++pt)
        acc[cti][pt] = __builtin_amdgcn_mfma_f32_16x16x32_bf16(afrag[cti][kt], bfr[pt], acc[cti][pt], 0, 0, 0);
  }

  // ======== epilogue: pure VALU dot + per-wave partial out ========
  float num = 0.f;
  #pragma unroll
  for (int pt = 0; pt < 4; ++pt) {
    float tmp = 0.f;
    #pragma unroll
    for (int cti = 0; cti < 2; ++cti)
      #pragma unroll
      for (int r = 0; r < 4; ++r)
        tmp = fmaf(bv[cti][pt][r], acc[cti][pt][r], tmp);
    num = fmaf(inb[pt], tmp, num);
  }
  float cntf = (float)cntpart;
  #pragma unroll
  for (int off = 32; off > 0; off >>= 1) {
    num  += __shfl_xor(num, off);
    cntf += __shfl_xor(cntf, off);
  }
  if (lane == 0) {
    ws_num[b * 8 + wv] = num;
    ws_cnt[b * 8 + wv] = cntf;
  }
}

__global__ __launch_bounds__(512) void pixpro_reduce(
    const float* __restrict__ ws_num, const float* __restrict__ ws_cnt,
    float* __restrict__ out)
{
  __shared__ float rn[8], rc[8];
  float n = 0.f, c = 0.f;
  for (int i = threadIdx.x; i < 16384; i += 512) { n += ws_num[i]; c += ws_cnt[i]; }
  #pragma unroll
  for (int off = 32; off > 0; off >>= 1) {
    n += __shfl_xor(n, off);
    c += __shfl_xor(c, off);
  }
  const int wv = threadIdx.x >> 6, lane = threadIdx.x & 63;
  if (lane == 0) { rn[wv] = n; rc[wv] = c; }
  __syncthreads();
  if (threadIdx.x == 0) {
    float N = 0.f, D = 0.f;
    #pragma unroll
    for (int i = 0; i < 8; ++i) { N += rn[i]; D += rc[i]; }
    out[0] = -(N / D);
  }
}

extern "C" void kernel_launch(void* const* d_in, const int* in_sizes, int n_in,
                              void* d_out, int out_size, void* d_ws, size_t ws_size,
                              hipStream_t stream) {
  const float* base   = (const float*)d_in[0];
  const float* moment = (const float*)d_in[1];
  const int*   A      = (const int*)d_in[2];
  float* ws_num = (float*)d_ws;            // 16384 floats
  float* ws_cnt = ws_num + 16384;          // 16384 floats (128 KB total)
  pixpro_main<<<2048, 512, 0, stream>>>(base, moment, A, ws_num, ws_cnt);
  pixpro_reduce<<<1, 512, 0, stream>>>(ws_num, ws_cnt, (float*)d_out);
}